// Round 1
// baseline (5931.530 us; speedup 1.0000x reference)
//
#include <hip/hip_runtime.h>
#include <math.h>

#define B 32
#define N 16384
#define DIM 64
#define HID 64
#define KD 16
#define DM 512
#define MP 16

// ---------------- Kernel 1: saliency = softplus(tanh(x@W1+b1) . w_s) ----------------
__global__ __launch_bounds__(256) void k_saliency(
    const float* __restrict__ x, const float* __restrict__ W1,
    const float* __restrict__ b1, const float* __restrict__ w_s,
    float* __restrict__ sal) {
  __shared__ float sW1[DIM * HID];   // [d][j]
  __shared__ float sb1[HID];
  __shared__ float sws[HID];
  for (int i = threadIdx.x; i < DIM * HID; i += 256) sW1[i] = W1[i];
  if (threadIdx.x < HID) {
    sb1[threadIdx.x] = b1[threadIdx.x];
    sws[threadIdx.x] = w_s[threadIdx.x];
  }
  __syncthreads();

  size_t pt = (size_t)blockIdx.x * 256 + threadIdx.x;   // < B*N
  const float4* xp = (const float4*)(x + pt * DIM);
  float xs[DIM];
#pragma unroll
  for (int i = 0; i < DIM / 4; ++i) {
    float4 v = xp[i];
    xs[4 * i + 0] = v.x; xs[4 * i + 1] = v.y;
    xs[4 * i + 2] = v.z; xs[4 * i + 3] = v.w;
  }

  float s = 0.f;
#pragma unroll 1
  for (int jb = 0; jb < 4; ++jb) {      // 16 hidden cols at a time (register budget)
    float acc[16];
#pragma unroll
    for (int j = 0; j < 16; ++j) acc[j] = sb1[jb * 16 + j];
#pragma unroll
    for (int d = 0; d < DIM; ++d) {
      float xd = xs[d];
#pragma unroll
      for (int q = 0; q < 4; ++q) {
        const float4 w = *(const float4*)&sW1[d * HID + jb * 16 + q * 4];
        acc[q * 4 + 0] = fmaf(xd, w.x, acc[q * 4 + 0]);
        acc[q * 4 + 1] = fmaf(xd, w.y, acc[q * 4 + 1]);
        acc[q * 4 + 2] = fmaf(xd, w.z, acc[q * 4 + 2]);
        acc[q * 4 + 3] = fmaf(xd, w.w, acc[q * 4 + 3]);
      }
    }
#pragma unroll
    for (int j = 0; j < 16; ++j) s = fmaf(sws[jb * 16 + j], tanhf(acc[j]), s);
  }
  // softplus, numerically stable, matches jax.nn.softplus
  float sp = fmaxf(s, 0.f) + log1pf(expf(-fabsf(s)));
  sal[pt] = sp;
}

// ------------- Kernel 2: per-row softmax stats, y_star, top-16 (one block per b) -------------
__global__ __launch_bounds__(256) void k_row(
    float* __restrict__ y,          // [B][N]: in = saliency, out = y_star
    int* __restrict__ top_idx,      // [B][MP]
    float* __restrict__ top_sal) {  // [B][MP]
  __shared__ float srow[N];   // 64 KB (gfx950: 160 KB LDS available)
  __shared__ float rv[256];
  __shared__ int   ri[256];
  __shared__ float s_max, s_sum;
  const int b = blockIdx.x, t = threadIdx.x;
  float* row = y + (size_t)b * N;

  // load + row max
  float m = -INFINITY;
  for (int i = t; i < N; i += 256) {
    float v = row[i];
    srow[i] = v;
    m = fmaxf(m, v);
  }
  rv[t] = m; __syncthreads();
  for (int s = 128; s > 0; s >>= 1) {
    if (t < s) rv[t] = fmaxf(rv[t], rv[t + s]);
    __syncthreads();
  }
  if (t == 0) s_max = rv[0];
  __syncthreads();
  const float mx = s_max;

  // sum of exp(s - max)
  float acc = 0.f;
  for (int i = t; i < N; i += 256) acc += expf(srow[i] - mx);
  rv[t] = acc; __syncthreads();
  for (int s = 128; s > 0; s >>= 1) {
    if (t < s) rv[t] += rv[t + s];
    __syncthreads();
  }
  if (t == 0) s_sum = rv[0];
  __syncthreads();
  const float inv = 1.f / s_sum;

  // y_star = 0.5*sigmoid(s) + 0.5*8*softmax(s)
  for (int i = t; i < N; i += 256) {
    float sv = srow[i];
    float sig = 1.f / (1.f + expf(-sv));
    row[i] = fmaf(0.5f, sig, 4.f * expf(sv - mx) * inv);
  }

  // top-16 on saliency (y_star strictly monotone in saliency => same ranking;
  // ties -> smallest index, matching jax.lax.top_k)
  for (int k = 0; k < MP; ++k) {
    float bv = -INFINITY; int bi = N;
    for (int i = t; i < N; i += 256) {
      float v = srow[i];
      if (v > bv) { bv = v; bi = i; }   // strict >: earliest (smallest) index kept
    }
    rv[t] = bv; ri[t] = bi; __syncthreads();
    for (int s = 128; s > 0; s >>= 1) {
      if (t < s) {
        if (rv[t + s] > rv[t] || (rv[t + s] == rv[t] && ri[t + s] < ri[t])) {
          rv[t] = rv[t + s]; ri[t] = ri[t + s];
        }
      }
      __syncthreads();
    }
    if (t == 0) {
      top_idx[b * MP + k] = ri[0];
      top_sal[b * MP + k] = rv[0];
      srow[ri[0]] = -INFINITY;
    }
    __syncthreads();
  }
}

// ------------- Kernel 3: gather selected rows, lift (66->16), project (16->512) -------------
__global__ __launch_bounds__(256) void k_tokens(
    const float* __restrict__ x,
    const int* __restrict__ top_idx, const float* __restrict__ top_sal,
    const float* __restrict__ W_lift, const float* __restrict__ b_lift,
    const float* __restrict__ W_proj, const float* __restrict__ b_proj,
    const float* __restrict__ mu, const float* __restrict__ sigma,
    float* __restrict__ tokens) {
  __shared__ float lifted[KD];
  const int bk = blockIdx.x;          // b*MP + k
  const int b = bk / MP;
  const int t = threadIdx.x;
  const int idx = top_idx[bk];
  const float salv = top_sal[bk];
  const float* xr = x + ((size_t)b * N + idx) * DIM;

  if (t < KD) {
    float acc = b_lift[t];
    for (int a = 0; a < DIM; ++a)
      acc = fmaf((xr[a] - mu[a]) / sigma[a], W_lift[a * KD + t], acc);
    acc = fmaf((salv - mu[64]) / sigma[64], W_lift[64 * KD + t], acc);
    float pos = (float)idx / (float)N;
    acc = fmaf((pos - mu[65]) / sigma[65], W_lift[65 * KD + t], acc);
    lifted[t] = acc;
  }
  __syncthreads();

  for (int d = t; d < DM; d += 256) {
    float acc = b_proj[d];
#pragma unroll
    for (int c = 0; c < KD; ++c) acc = fmaf(lifted[c], W_proj[c * DM + d], acc);
    tokens[(size_t)bk * DM + d] = acc;
  }
}

extern "C" void kernel_launch(void* const* d_in, const int* in_sizes, int n_in,
                              void* d_out, int out_size, void* d_ws, size_t ws_size,
                              hipStream_t stream) {
  const float* x      = (const float*)d_in[0];
  const float* W1     = (const float*)d_in[1];
  const float* b1     = (const float*)d_in[2];
  // d_in[3] = w_e (unused by the reference outputs)
  const float* w_s    = (const float*)d_in[4];
  const float* W_lift = (const float*)d_in[5];
  const float* b_lift = (const float*)d_in[6];
  const float* W_proj = (const float*)d_in[7];
  const float* b_proj = (const float*)d_in[8];
  const float* mu     = (const float*)d_in[9];
  const float* sigma  = (const float*)d_in[10];

  float* tokens = (float*)d_out;                       // [B, MP, DM]
  float* ystar  = (float*)d_out + (size_t)B * MP * DM; // [B, N]
  int*   top_idx = (int*)d_ws;                         // 512 ints
  float* top_sal = (float*)((char*)d_ws + B * MP * sizeof(int));

  k_saliency<<<(B * N) / 256, 256, 0, stream>>>(x, W1, b1, w_s, ystar);
  k_row<<<B, 256, 0, stream>>>(ystar, top_idx, top_sal);
  k_tokens<<<B * MP, 256, 0, stream>>>(x, top_idx, top_sal, W_lift, b_lift,
                                       W_proj, b_proj, mu, sigma, tokens);
}

// Round 2
// 180.606 us; speedup vs baseline: 32.8423x; 32.8423x over previous
//
#include <hip/hip_runtime.h>
#include <math.h>

#define B 32
#define N 16384
#define DIM 64
#define HID 64
#define KD 16
#define DM 512
#define MP 16

__device__ __forceinline__ float fast_tanh(float a) {
  // tanh(a) = 1 - 2/(exp(2a)+1); exact at +-inf, ~1e-6 abs error.
  float e = __expf(2.f * a);
  return 1.f - 2.f / (e + 1.f);
}

// ---------------- Kernel 1: saliency = softplus(tanh(x@W1+b1) . w_s) ----------------
// One point per thread. acc[64] in VGPRs; x streamed float4-at-a-time;
// W1/b1/w_s read via wave-uniform addresses -> scalar loads (SGPR operand in FMA).
__global__ __launch_bounds__(256) void k_saliency(
    const float* __restrict__ x, const float* __restrict__ W1,
    const float* __restrict__ b1, const float* __restrict__ w_s,
    float* __restrict__ sal) {
  const size_t pt = (size_t)blockIdx.x * 256 + threadIdx.x;  // < B*N
  const float4* __restrict__ xp = (const float4*)(x + pt * DIM);

  float acc[HID];
#pragma unroll
  for (int j = 0; j < HID; ++j) acc[j] = b1[j];  // uniform -> s_load

#pragma unroll
  for (int i = 0; i < DIM / 4; ++i) {
    const float4 xv = xp[i];
    const float xd[4] = {xv.x, xv.y, xv.z, xv.w};
#pragma unroll
    for (int q = 0; q < 4; ++q) {
      const int d = 4 * i + q;
      const float* __restrict__ wrow = W1 + d * HID;  // uniform row
#pragma unroll
      for (int j = 0; j < HID; ++j)
        acc[j] = fmaf(xd[q], wrow[j], acc[j]);  // 1 SGPR + 2 VGPR operands
    }
  }

  float s = 0.f;
#pragma unroll
  for (int j = 0; j < HID; ++j) s = fmaf(w_s[j], fast_tanh(acc[j]), s);

  // softplus, numerically stable, matches jax.nn.softplus
  const float sp = fmaxf(s, 0.f) + log1pf(__expf(-fabsf(s)));
  sal[pt] = sp;
}

// ------------- Kernel 2: per-row softmax stats, y_star, top-16 (one block per b) -------------
__global__ __launch_bounds__(256) void k_row(
    float* __restrict__ y,          // [B][N]: in = saliency, out = y_star
    int* __restrict__ top_idx,      // [B][MP]
    float* __restrict__ top_sal) {  // [B][MP]
  __shared__ float srow[N];   // 64 KB
  __shared__ float rv[256];
  __shared__ int   ri[256];
  __shared__ float s_max, s_sum;
  const int b = blockIdx.x, t = threadIdx.x;
  float* row = y + (size_t)b * N;

  // load + row max
  float m = -INFINITY;
  for (int i = t; i < N; i += 256) {
    float v = row[i];
    srow[i] = v;
    m = fmaxf(m, v);
  }
  rv[t] = m; __syncthreads();
  for (int s = 128; s > 0; s >>= 1) {
    if (t < s) rv[t] = fmaxf(rv[t], rv[t + s]);
    __syncthreads();
  }
  if (t == 0) s_max = rv[0];
  __syncthreads();
  const float mx = s_max;

  // sum of exp(s - max)
  float acc = 0.f;
  for (int i = t; i < N; i += 256) acc += expf(srow[i] - mx);
  rv[t] = acc; __syncthreads();
  for (int s = 128; s > 0; s >>= 1) {
    if (t < s) rv[t] += rv[t + s];
    __syncthreads();
  }
  if (t == 0) s_sum = rv[0];
  __syncthreads();
  const float inv = 1.f / s_sum;

  // y_star = 0.5*sigmoid(s) + 0.5*8*softmax(s)
  for (int i = t; i < N; i += 256) {
    float sv = srow[i];
    float sig = 1.f / (1.f + expf(-sv));
    row[i] = fmaf(0.5f, sig, 4.f * expf(sv - mx) * inv);
  }

  // top-16 on saliency (y_star strictly monotone in saliency => same ranking;
  // ties -> smallest index, matching jax.lax.top_k)
  for (int k = 0; k < MP; ++k) {
    float bv = -INFINITY; int bi = N;
    for (int i = t; i < N; i += 256) {
      float v = srow[i];
      if (v > bv) { bv = v; bi = i; }   // strict >: earliest (smallest) index kept
    }
    rv[t] = bv; ri[t] = bi; __syncthreads();
    for (int s = 128; s > 0; s >>= 1) {
      if (t < s) {
        if (rv[t + s] > rv[t] || (rv[t + s] == rv[t] && ri[t + s] < ri[t])) {
          rv[t] = rv[t + s]; ri[t] = ri[t + s];
        }
      }
      __syncthreads();
    }
    if (t == 0) {
      top_idx[b * MP + k] = ri[0];
      top_sal[b * MP + k] = rv[0];
      srow[ri[0]] = -INFINITY;
    }
    __syncthreads();
  }
}

// ------------- Kernel 3: gather selected rows, lift (66->16), project (16->512) -------------
__global__ __launch_bounds__(256) void k_tokens(
    const float* __restrict__ x,
    const int* __restrict__ top_idx, const float* __restrict__ top_sal,
    const float* __restrict__ W_lift, const float* __restrict__ b_lift,
    const float* __restrict__ W_proj, const float* __restrict__ b_proj,
    const float* __restrict__ mu, const float* __restrict__ sigma,
    float* __restrict__ tokens) {
  __shared__ float lifted[KD];
  const int bk = blockIdx.x;          // b*MP + k
  const int b = bk / MP;
  const int t = threadIdx.x;
  const int idx = top_idx[bk];
  const float salv = top_sal[bk];
  const float* xr = x + ((size_t)b * N + idx) * DIM;

  if (t < KD) {
    float acc = b_lift[t];
    for (int a = 0; a < DIM; ++a)
      acc = fmaf((xr[a] - mu[a]) / sigma[a], W_lift[a * KD + t], acc);
    acc = fmaf((salv - mu[64]) / sigma[64], W_lift[64 * KD + t], acc);
    float pos = (float)idx / (float)N;
    acc = fmaf((pos - mu[65]) / sigma[65], W_lift[65 * KD + t], acc);
    lifted[t] = acc;
  }
  __syncthreads();

  for (int d = t; d < DM; d += 256) {
    float acc = b_proj[d];
#pragma unroll
    for (int c = 0; c < KD; ++c) acc = fmaf(lifted[c], W_proj[c * DM + d], acc);
    tokens[(size_t)bk * DM + d] = acc;
  }
}

extern "C" void kernel_launch(void* const* d_in, const int* in_sizes, int n_in,
                              void* d_out, int out_size, void* d_ws, size_t ws_size,
                              hipStream_t stream) {
  const float* x      = (const float*)d_in[0];
  const float* W1     = (const float*)d_in[1];
  const float* b1     = (const float*)d_in[2];
  // d_in[3] = w_e (unused by the reference outputs)
  const float* w_s    = (const float*)d_in[4];
  const float* W_lift = (const float*)d_in[5];
  const float* b_lift = (const float*)d_in[6];
  const float* W_proj = (const float*)d_in[7];
  const float* b_proj = (const float*)d_in[8];
  const float* mu     = (const float*)d_in[9];
  const float* sigma  = (const float*)d_in[10];

  float* tokens = (float*)d_out;                       // [B, MP, DM]
  float* ystar  = (float*)d_out + (size_t)B * MP * DM; // [B, N]
  int*   top_idx = (int*)d_ws;                         // 512 ints
  float* top_sal = (float*)((char*)d_ws + B * MP * sizeof(int));

  k_saliency<<<(B * N) / 256, 256, 0, stream>>>(x, W1, b1, w_s, ystar);
  k_row<<<B, 256, 0, stream>>>(ystar, top_idx, top_sal);
  k_tokens<<<B * MP, 256, 0, stream>>>(x, top_idx, top_sal, W_lift, b_lift,
                                       W_proj, b_proj, mu, sigma, tokens);
}

// Round 4
// 107.119 us; speedup vs baseline: 55.3733x; 1.6860x over previous
//
#include <hip/hip_runtime.h>
#include <math.h>

#define B 32
#define N 16384
#define DIM 64
#define HID 64
#define KD 16
#define DM 512
#define MP 16

typedef __attribute__((ext_vector_type(8))) short bf16x8;
typedef __attribute__((ext_vector_type(4))) float f32x4;

__device__ __forceinline__ float fast_tanh(float a) {
  float e = __expf(2.f * a);
  return 1.f - 2.f / (e + 1.f);   // exact at +-inf, ~1e-6 abs err
}
__device__ __forceinline__ ushort f2bf(float f) {   // round-to-nearest-even
  unsigned u = __float_as_uint(f);
  u += 0x7fffu + ((u >> 16) & 1u);
  return (ushort)(u >> 16);
}
__device__ __forceinline__ float bf2f(ushort h) {
  return __uint_as_float((unsigned)h << 16);
}
// XOR-swizzle within a 128-byte row (8x 16B granules) — kills the stride-128B
// bank conflict on ds_read_b128 (guide §6 G4); applied on write AND read.
__device__ __forceinline__ int swz(int row, int byteoff) {
  return row * 128 + (byteoff ^ ((row & 7) << 4));
}

// ---------- Kernel 1: saliency via bf16x3 MFMA GEMM + fused tanh/dot/softplus ----------
// Block: 256 thr (4 waves), 128 x-rows. acc = x_hi@W_hi + x_lo@W_hi + x_hi@W_lo.
__global__ __launch_bounds__(256) void k_saliency(
    const float* __restrict__ x, const float* __restrict__ W1,
    const float* __restrict__ b1, const float* __restrict__ w_s,
    float* __restrict__ sal) {
  __shared__ ushort sAhi[128 * 64], sAlo[128 * 64];   // x tile hi/lo (swizzled)
  __shared__ ushort sBhi[64 * 64],  sBlo[64 * 64];    // W1^T hi/lo (swizzled), [hid][k]
  const int t = threadIdx.x;
  const int rowbase = blockIdx.x * 128;

  // stage x tile: 2048 float4, 8 per thread, coalesced
  const float4* __restrict__ xg = (const float4*)(x + (size_t)rowbase * DIM);
#pragma unroll
  for (int i = 0; i < 8; ++i) {
    const int idx = t + 256 * i;            // float4 index in tile
    const float4 v = xg[idx];
    const int row = idx >> 4;               // 16 float4 per 64-float row
    const int off = (idx & 15) * 8;         // byte offset of 4 ushorts
    ushort h0 = f2bf(v.x), h1 = f2bf(v.y), h2 = f2bf(v.z), h3 = f2bf(v.w);
    ushort l0 = f2bf(v.x - bf2f(h0)), l1 = f2bf(v.y - bf2f(h1));
    ushort l2 = f2bf(v.z - bf2f(h2)), l3 = f2bf(v.w - bf2f(h3));
    uint2 hp, lp;
    hp.x = (unsigned)h0 | ((unsigned)h1 << 16); hp.y = (unsigned)h2 | ((unsigned)h3 << 16);
    lp.x = (unsigned)l0 | ((unsigned)l1 << 16); lp.y = (unsigned)l2 | ((unsigned)l3 << 16);
    *(uint2*)((char*)sAhi + swz(row, off)) = hp;
    *(uint2*)((char*)sAlo + swz(row, off)) = lp;
  }
  // stage W1 transposed: W1[k][h] -> sB[h][k]
  const float4* __restrict__ wg = (const float4*)W1;
#pragma unroll
  for (int i = 0; i < 4; ++i) {
    const int idx = t + 256 * i;            // 1024 float4
    const float4 v = wg[idx];
    const int k = idx >> 4, h0 = (idx & 15) * 4;
    const float vv[4] = {v.x, v.y, v.z, v.w};
#pragma unroll
    for (int j = 0; j < 4; ++j) {
      ushort hi = f2bf(vv[j]);
      ushort lo = f2bf(vv[j] - bf2f(hi));
      *(ushort*)((char*)sBhi + swz(h0 + j, k * 2)) = hi;
      *(ushort*)((char*)sBlo + swz(h0 + j, k * 2)) = lo;
    }
  }
  __syncthreads();

  const int lane = t & 63, wid = t >> 6;
  f32x4 acc[2][4];   // [row-tile][hid-tile]
#pragma unroll
  for (int rt = 0; rt < 2; ++rt)
#pragma unroll
    for (int ct = 0; ct < 4; ++ct) acc[rt][ct] = (f32x4)0.f;

#pragma unroll
  for (int kc = 0; kc < 2; ++kc) {
    const int koff = kc * 64 + (lane >> 4) * 16;   // byte offset of this lane's 8 k-elems
    bf16x8 aHi[2], aLo[2];
#pragma unroll
    for (int rt = 0; rt < 2; ++rt) {
      const int row = wid * 32 + rt * 16 + (lane & 15);
      aHi[rt] = *(const bf16x8*)((const char*)sAhi + swz(row, koff));
      aLo[rt] = *(const bf16x8*)((const char*)sAlo + swz(row, koff));
    }
#pragma unroll
    for (int ct = 0; ct < 4; ++ct) {
      const int col = ct * 16 + (lane & 15);
      const bf16x8 bHi = *(const bf16x8*)((const char*)sBhi + swz(col, koff));
      const bf16x8 bLo = *(const bf16x8*)((const char*)sBlo + swz(col, koff));
#pragma unroll
      for (int rt = 0; rt < 2; ++rt) {
        acc[rt][ct] = __builtin_amdgcn_mfma_f32_16x16x32_bf16(aHi[rt], bHi, acc[rt][ct], 0, 0, 0);
        acc[rt][ct] = __builtin_amdgcn_mfma_f32_16x16x32_bf16(aLo[rt], bHi, acc[rt][ct], 0, 0, 0);
        acc[rt][ct] = __builtin_amdgcn_mfma_f32_16x16x32_bf16(aHi[rt], bLo, acc[rt][ct], 0, 0, 0);
      }
    }
  }

  // epilogue: s_row = sum_hid w_s[hid] * tanh(acc + b1[hid]); C layout: col=lane&15, row=(lane>>4)*4+reg
  const int cb = lane & 15;
  float ws4[4], b14[4];
#pragma unroll
  for (int ct = 0; ct < 4; ++ct) { ws4[ct] = w_s[ct * 16 + cb]; b14[ct] = b1[ct * 16 + cb]; }
#pragma unroll
  for (int rt = 0; rt < 2; ++rt) {
    float s[4] = {0.f, 0.f, 0.f, 0.f};
#pragma unroll
    for (int ct = 0; ct < 4; ++ct)
#pragma unroll
      for (int r = 0; r < 4; ++r)
        s[r] = fmaf(ws4[ct], fast_tanh(acc[rt][ct][r] + b14[ct]), s[r]);
#pragma unroll
    for (int r = 0; r < 4; ++r) {
#pragma unroll
      for (int off = 1; off < 16; off <<= 1) s[r] += __shfl_xor(s[r], off);
    }
    if ((lane & 15) == 0) {
#pragma unroll
      for (int r = 0; r < 4; ++r) {
        const int grow = rowbase + wid * 32 + rt * 16 + (lane >> 4) * 4 + r;
        const float sv = s[r];
        sal[grow] = fmaxf(sv, 0.f) + log1pf(__expf(-fabsf(sv)));   // softplus
      }
    }
  }
}

// ---------- Kernel 2: per-chunk (2048 elems) online-softmax partials + top-16 ----------
// Indices stored WITHIN-ROW (0..N-1): chunk c covers row (c>>3), row-offset (c&7)*2048.
__global__ __launch_bounds__(256) void k_chunk(
    const float* __restrict__ sal, float* __restrict__ cmax, float* __restrict__ csum,
    float* __restrict__ cval, int* __restrict__ cidx) {
  __shared__ float sb[4], ss[4], wv[4];
  __shared__ int wi[4];
  const int t = threadIdx.x, c = blockIdx.x;
  const int rowoff = (c & 7) * 2048;          // within-row offset of this chunk
  const size_t gbase = (size_t)c * 2048;      // flat offset into sal
  float v[8];
#pragma unroll
  for (int j = 0; j < 8; ++j) v[j] = sal[gbase + t + 256 * j];

  float m = v[0];
#pragma unroll
  for (int j = 1; j < 8; ++j) m = fmaxf(m, v[j]);
#pragma unroll
  for (int off = 1; off < 64; off <<= 1) m = fmaxf(m, __shfl_xor(m, off));
  if ((t & 63) == 0) sb[t >> 6] = m;
  __syncthreads();
  m = fmaxf(fmaxf(sb[0], sb[1]), fmaxf(sb[2], sb[3]));

  float se = 0.f;
#pragma unroll
  for (int j = 0; j < 8; ++j) se += __expf(v[j] - m);
#pragma unroll
  for (int off = 1; off < 64; off <<= 1) se += __shfl_xor(se, off);
  if ((t & 63) == 0) ss[t >> 6] = se;
  __syncthreads();
  if (t == 0) { cmax[c] = m; csum[c] = ss[0] + ss[1] + ss[2] + ss[3]; }

  // top-16 of chunk, (value desc, index asc), indices within-row
  for (int k = 0; k < MP; ++k) {
    float bv = v[0]; int bj = 0;
#pragma unroll
    for (int j = 1; j < 8; ++j)
      if (v[j] > bv) { bv = v[j]; bj = j; }      // strict >: keeps smallest idx in-thread
    int bi = rowoff + t + 256 * bj;
#pragma unroll
    for (int off = 1; off < 64; off <<= 1) {
      const float ov = __shfl_xor(bv, off);
      const int   oi = __shfl_xor(bi, off);
      if (ov > bv || (ov == bv && oi < bi)) { bv = ov; bi = oi; }
    }
    if ((t & 63) == 0) { wv[t >> 6] = bv; wi[t >> 6] = bi; }
    __syncthreads();
    float Bv = wv[0]; int Bi = wi[0];
#pragma unroll
    for (int w = 1; w < 4; ++w)
      if (wv[w] > Bv || (wv[w] == Bv && wi[w] < Bi)) { Bv = wv[w]; Bi = wi[w]; }
    if (t == 0) { cval[c * MP + k] = Bv; cidx[c * MP + k] = Bi; }
    // deflate winner (static indexing — no scratch)
    const int relidx = Bi - rowoff;
#pragma unroll
    for (int jj = 0; jj < 8; ++jj)
      if (relidx == t + 256 * jj) v[jj] = -INFINITY;
    __syncthreads();
  }
}

// ---------- Kernel 3: merge 8 chunks per row -> row stats + global top-16 ----------
__global__ __launch_bounds__(256) void k_merge(
    const float* __restrict__ cmax, const float* __restrict__ csum,
    const float* __restrict__ cval, const int* __restrict__ cidx,
    float* __restrict__ rowmax, float* __restrict__ rowinv,
    int* __restrict__ top_idx, float* __restrict__ top_sal) {
  __shared__ float wv[4];
  __shared__ int wi[4];
  const int b = blockIdx.x, t = threadIdx.x;
  if (t == 0) {
    float mx = cmax[b * 8];
#pragma unroll
    for (int c = 1; c < 8; ++c) mx = fmaxf(mx, cmax[b * 8 + c]);
    float S = 0.f;
#pragma unroll
    for (int c = 0; c < 8; ++c) S += csum[b * 8 + c] * __expf(cmax[b * 8 + c] - mx);
    rowmax[b] = mx; rowinv[b] = 1.f / S;
  }
  float v = -INFINITY; int i = 0x7fffffff;
  if (t < 128) { v = cval[b * 128 + t]; i = cidx[b * 128 + t]; }
  for (int k = 0; k < MP; ++k) {
    float bv = v; int bi = i;
#pragma unroll
    for (int off = 1; off < 64; off <<= 1) {
      const float ov = __shfl_xor(bv, off);
      const int   oi = __shfl_xor(bi, off);
      if (ov > bv || (ov == bv && oi < bi)) { bv = ov; bi = oi; }
    }
    if ((t & 63) == 0) { wv[t >> 6] = bv; wi[t >> 6] = bi; }
    __syncthreads();
    float Bv = wv[0]; int Bi = wi[0];
#pragma unroll
    for (int w = 1; w < 4; ++w)
      if (wv[w] > Bv || (wv[w] == Bv && wi[w] < Bi)) { Bv = wv[w]; Bi = wi[w]; }
    if (t == 0) { top_idx[b * MP + k] = Bi; top_sal[b * MP + k] = Bv; }
    if (i == Bi) v = -INFINITY;
    __syncthreads();
  }
}

// ---------- Kernel 4: y_star elementwise ----------
__global__ __launch_bounds__(256) void k_ystar(
    float* __restrict__ y, const float* __restrict__ rowmax, const float* __restrict__ rowinv) {
  const int gi = blockIdx.x * 256 + threadIdx.x;
  const int b = gi >> 14;                       // N = 16384
  const float mx = rowmax[b], inv = rowinv[b];
  const float v = y[gi];
  const float sig = 1.f / (1.f + __expf(-v));
  y[gi] = fmaf(0.5f, sig, 4.f * __expf(v - mx) * inv);
}

// ---------- Kernel 5: gather + lift (66->16) + project (16->512) ----------
__global__ __launch_bounds__(256) void k_tokens(
    const float* __restrict__ x,
    const int* __restrict__ top_idx, const float* __restrict__ top_sal,
    const float* __restrict__ W_lift, const float* __restrict__ b_lift,
    const float* __restrict__ W_proj, const float* __restrict__ b_proj,
    const float* __restrict__ mu, const float* __restrict__ sigma,
    float* __restrict__ tokens) {
  __shared__ float part[16][17];
  __shared__ float lifted[KD];
  const int bk = blockIdx.x, b = bk >> 4, t = threadIdx.x;
  const int kd = t & 15, seg = t >> 4;
  const int idx = top_idx[bk];                  // within-row index (0..N-1)
  const float salv = top_sal[bk];
  const float* __restrict__ xr = x + ((size_t)b * N + idx) * DIM;

  float p = 0.f;
#pragma unroll
  for (int u = 0; u < 4; ++u) {
    const int a = seg * 4 + u;
    p = fmaf((xr[a] - mu[a]) / sigma[a], W_lift[a * KD + kd], p);
  }
  if (seg == 0) p = fmaf((salv - mu[64]) / sigma[64], W_lift[64 * KD + kd], p);
  if (seg == 1) {
    const float pos = (float)idx / (float)N;
    p = fmaf((pos - mu[65]) / sigma[65], W_lift[65 * KD + kd], p);
  }
  part[seg][kd] = p;
  __syncthreads();
  if (t < KD) {
    float s = b_lift[t];
#pragma unroll
    for (int g = 0; g < 16; ++g) s += part[g][t];
    lifted[t] = s;
  }
  __syncthreads();

  const float2* __restrict__ Wp2 = (const float2*)W_proj;
  float2 a2 = ((const float2*)b_proj)[t];
#pragma unroll
  for (int c = 0; c < KD; ++c) {
    const float2 w = Wp2[c * 256 + t];
    a2.x = fmaf(lifted[c], w.x, a2.x);
    a2.y = fmaf(lifted[c], w.y, a2.y);
  }
  ((float2*)(tokens + (size_t)bk * DM))[t] = a2;
}

extern "C" void kernel_launch(void* const* d_in, const int* in_sizes, int n_in,
                              void* d_out, int out_size, void* d_ws, size_t ws_size,
                              hipStream_t stream) {
  const float* x      = (const float*)d_in[0];
  const float* W1     = (const float*)d_in[1];
  const float* b1     = (const float*)d_in[2];
  // d_in[3] = w_e (unused by the reference outputs)
  const float* w_s    = (const float*)d_in[4];
  const float* W_lift = (const float*)d_in[5];
  const float* b_lift = (const float*)d_in[6];
  const float* W_proj = (const float*)d_in[7];
  const float* b_proj = (const float*)d_in[8];
  const float* mu     = (const float*)d_in[9];
  const float* sigma  = (const float*)d_in[10];

  float* tokens = (float*)d_out;                       // [B, MP, DM]
  float* ystar  = (float*)d_out + (size_t)B * MP * DM; // [B, N] (saliency staged here)

  // workspace layout (floats): ~39 KB total
  int*   top_idx = (int*)d_ws;                 // 512
  float* top_sal = (float*)d_ws + 512;         // 512
  float* cmax    = (float*)d_ws + 1024;        // 256
  float* csum    = (float*)d_ws + 1280;        // 256
  float* rowmax  = (float*)d_ws + 1536;        // 32
  float* rowinv  = (float*)d_ws + 1568;        // 32
  float* cval    = (float*)d_ws + 1600;        // 4096
  int*   cidx    = (int*)d_ws + 5696;          // 4096

  k_saliency<<<(B * N) / 128, 256, 0, stream>>>(x, W1, b1, w_s, ystar);
  k_chunk<<<(B * N) / 2048, 256, 0, stream>>>(ystar, cmax, csum, cval, cidx);
  k_merge<<<B, 256, 0, stream>>>(cmax, csum, cval, cidx, rowmax, rowinv, top_idx, top_sal);
  k_ystar<<<(B * N) / 256, 256, 0, stream>>>(ystar, rowmax, rowinv);
  k_tokens<<<B * MP, 256, 0, stream>>>(x, top_idx, top_sal, W_lift, b_lift,
                                       W_proj, b_proj, mu, sigma, tokens);
}